// Round 10
// baseline (415.786 us; speedup 1.0000x reference)
//
#include <hip/hip_runtime.h>
#include <hip/hip_bf16.h>

#define D_MODEL 1024
#define NHEAD   16
#define HEAD_DIM 64
#define BATCH   2
#define SEQ     2048
#define NTOK    (BATCH*SEQ)   // 4096

// log2(10000)/64
#define FREQ_LOG2 0.20762050593046015f

typedef short  bfrag __attribute__((ext_vector_type(8)));  // 8 bf16 = 4 VGPR
typedef float  ffrag __attribute__((ext_vector_type(4)));  // C/D frag

__device__ inline ushort f2bf(float x) {
    __hip_bfloat16 h = __float2bfloat16(x);
    return __builtin_bit_cast(ushort, h);
}
__device__ inline void split_bf(float x, ushort& hi, ushort& lo) {
    __hip_bfloat16 h = __float2bfloat16(x);
    hi = __builtin_bit_cast(ushort, h);
    lo = f2bf(x - __bfloat162float(h));
}

// ---------------------------------------------------------------------------
// Pre-pass 1: split data -> Ahi, Alo  (bf16 hi/lo), [4096][1024]
// ---------------------------------------------------------------------------
__global__ __launch_bounds__(256)
void split_data(const float* __restrict__ x, ushort* __restrict__ hi,
                ushort* __restrict__ lo)
{
    const int i4 = (blockIdx.x * 256 + threadIdx.x) * 4;
    const float4 v = *(const float4*)(x + i4);
    ushort4 h, l;
    split_bf(v.x, h.x, l.x); split_bf(v.y, h.y, l.y);
    split_bf(v.z, h.z, l.z); split_bf(v.w, h.w, l.w);
    *(ushort4*)(hi + i4) = h;
    *(ushort4*)(lo + i4) = l;
}

// ---------------------------------------------------------------------------
// Pre-pass 2: W[k][n] -> WT[n][k], plain bf16.  grid (16,16,3)
// ---------------------------------------------------------------------------
__global__ __launch_bounds__(256)
void split_tr_w(const float* __restrict__ Wq, const float* __restrict__ Wk,
                const float* __restrict__ Wv, ushort* __restrict__ hi)
{
    const int z = blockIdx.z;
    const float* W = (z == 0) ? Wq : (z == 1) ? Wk : Wv;
    ushort* thi = hi + (size_t)z * D_MODEL * D_MODEL;

    __shared__ float T[64][65];
    const int t  = threadIdx.x;
    const int k0 = blockIdx.x * 64, n0 = blockIdx.y * 64;

    #pragma unroll
    for (int i = 0; i < 4; i++) {
        const int f = i * 256 + t, r = f >> 4, c = (f & 15) * 4;
        const float4 v = *(const float4*)(W + (size_t)(k0 + r) * D_MODEL + n0 + c);
        T[r][c] = v.x; T[r][c + 1] = v.y; T[r][c + 2] = v.z; T[r][c + 3] = v.w;
    }
    __syncthreads();
    #pragma unroll
    for (int i = 0; i < 4; i++) {
        const int f = i * 256 + t, nr = f >> 4, kc = (f & 15) * 4;
        ushort4 h;
        h.x = f2bf(T[kc + 0][nr]);
        h.y = f2bf(T[kc + 1][nr]);
        h.z = f2bf(T[kc + 2][nr]);
        h.w = f2bf(T[kc + 3][nr]);
        const size_t o = (size_t)(n0 + nr) * D_MODEL + k0 + kc;
        *(ushort4*)(thi + o) = h;
    }
}

// ---------------------------------------------------------------------------
// Pre-pass 3: maskT[k][q] = mask[q][k].  grid (32,32). Runs AFTER gemm_qkv
// (its output overwrites the then-dead Ahi/Alo region of d_ws).
// ---------------------------------------------------------------------------
__global__ __launch_bounds__(256)
void tr_mask(const float* __restrict__ m, float* __restrict__ mt)
{
    __shared__ float T[64][65];
    const int t  = threadIdx.x;
    const int r0 = blockIdx.x * 64, c0 = blockIdx.y * 64;

    #pragma unroll
    for (int i = 0; i < 4; i++) {
        const int f = i * 256 + t, r = f >> 4, c = (f & 15) * 4;
        const float4 v = *(const float4*)(m + (size_t)(r0 + r) * SEQ + c0 + c);
        T[r][c] = v.x; T[r][c + 1] = v.y; T[r][c + 2] = v.z; T[r][c + 3] = v.w;
    }
    __syncthreads();
    #pragma unroll
    for (int i = 0; i < 4; i++) {
        const int f = i * 256 + t, rT = f >> 4, cT = (f & 15) * 4;
        float4 v;
        v.x = T[cT + 0][rT]; v.y = T[cT + 1][rT];
        v.z = T[cT + 2][rT]; v.w = T[cT + 3][rT];
        *(float4*)(mt + (size_t)(c0 + rT) * SEQ + r0 + cT) = v;
    }
}

// ---------------------------------------------------------------------------
// Kernel 3: bf16x2 GEMM 128x128xBK32, BARRIER-FREE K-loop: per-wave MFMA
// fragments loaded directly global->VGPR (contiguous 16B/lane; L1/L2 serve
// the in-block 2x reuse), 2-stage ping-pong software pipeline. LDS used only
// for the epilogue C repack. z=0 -> Q hi/lo (x1/8); z=1 -> K hi; z=2 -> VT.
// ---------------------------------------------------------------------------
struct GFrags { bfrag a[4], l[4], b[4]; };

__device__ __forceinline__ void load_frags(GFrags& f, const ushort* Ab,
                                           const ushort* Lb, const ushort* Bb,
                                           int k0)
{
    #pragma unroll
    for (int mt = 0; mt < 4; mt++) {
        f.a[mt] = *(const bfrag*)(Ab + (size_t)mt * 16 * D_MODEL + k0);
        f.l[mt] = *(const bfrag*)(Lb + (size_t)mt * 16 * D_MODEL + k0);
        f.b[mt] = *(const bfrag*)(Bb + (size_t)mt * 16 * D_MODEL + k0);
    }
}

__device__ __forceinline__ void do_mfma(ffrag (&acc)[4][4], const GFrags& f)
{
    #pragma unroll
    for (int nt = 0; nt < 4; nt++)
        #pragma unroll
        for (int mt = 0; mt < 4; mt++) {
            ffrag a = acc[mt][nt];
            a = __builtin_amdgcn_mfma_f32_16x16x32_bf16(f.a[mt], f.b[nt], a, 0, 0, 0);
            a = __builtin_amdgcn_mfma_f32_16x16x32_bf16(f.l[mt], f.b[nt], a, 0, 0, 0);
            acc[mt][nt] = a;
        }
}

__global__ __launch_bounds__(256, 2)
void gemm_qkv(const ushort* __restrict__ Ahi, const ushort* __restrict__ Alo,
              const ushort* __restrict__ WThi,
              const float* __restrict__ bq, const float* __restrict__ bk,
              const float* __restrict__ bv, const float* __restrict__ temporal,
              ushort* __restrict__ Qhi, ushort* __restrict__ Qlo,
              ushort* __restrict__ Khi,
              ushort* __restrict__ VT)
{
    __shared__ float cbuf[64 * 132];
    const int z  = blockIdx.z;
    const int m0 = blockIdx.x * 128;
    const int n0 = blockIdx.y * 128;
    const float* bias = (z == 0) ? bq : (z == 1) ? bk : bv;
    const ushort* Bh = WThi + (size_t)z * D_MODEL * D_MODEL;

    const int t = threadIdx.x;
    const int w = t >> 6, lane = t & 63;
    const int lane15 = lane & 15, quad8 = (lane >> 4) * 8, quad = lane >> 4;
    const int wm = (w >> 1) * 64, wn = (w & 1) * 64;

    ffrag acc[4][4];
    #pragma unroll
    for (int i = 0; i < 4; i++)
        #pragma unroll
        for (int j = 0; j < 4; j++) acc[i][j] = (ffrag){0.f, 0.f, 0.f, 0.f};

    const ushort* Ab = Ahi + (size_t)(m0 + wm + lane15) * D_MODEL + quad8;
    const ushort* Lb = Alo + (size_t)(m0 + wm + lane15) * D_MODEL + quad8;
    const ushort* Bb = Bh  + (size_t)(n0 + wn + lane15) * D_MODEL + quad8;

    GFrags fA, fB;
    load_frags(fA, Ab, Lb, Bb, 0);
    for (int k0 = 0; k0 < D_MODEL; k0 += 64) {
        load_frags(fB, Ab, Lb, Bb, k0 + 32);
        do_mfma(acc, fA);
        const int kn = (k0 + 64 < D_MODEL) ? k0 + 64 : 0;
        load_frags(fA, Ab, Lb, Bb, kn);
        do_mfma(acc, fB);
    }

    float bn[4];
    #pragma unroll
    for (int nt = 0; nt < 4; nt++) bn[nt] = bias[n0 + wn + nt * 16 + lane15];

    const int CST = (z == 2) ? 129 : 132;

    #pragma unroll
    for (int p = 0; p < 2; p++) {
        if (p) __syncthreads();
        if ((w >> 1) == p) {
            #pragma unroll
            for (int mt = 0; mt < 4; mt++)
                #pragma unroll
                for (int nt = 0; nt < 4; nt++)
                    #pragma unroll
                    for (int rr = 0; rr < 4; rr++)
                        cbuf[(mt * 16 + quad * 4 + rr) * CST + wn + nt * 16 + lane15] =
                            acc[mt][nt][rr] + bn[nt];
        }
        __syncthreads();

        if (z < 2) {
            ushort* ohi = (z == 0) ? Qhi : Khi;
            const float sc = (z == 0) ? 0.125f : 1.0f;
            #pragma unroll
            for (int i = 0; i < 8; i++) {
                const int f = i * 256 + t, r = f >> 5, c4 = (f & 31) * 4;
                float4 v = *(float4*)&cbuf[r * 132 + c4];
                const int m = m0 + p * 64 + r;
                const float tv = temporal[m];
                const float fr0 = exp2f(-(float)(c4 & 63) * FREQ_LOG2);
                const float fr1 = exp2f(-(float)((c4 + 2) & 63) * FREQ_LOG2);
                float s0, c0, s1, c1v;
                __sincosf(tv * fr0, &s0, &c0);
                __sincosf(tv * fr1, &s1, &c1v);
                const float y0 = (v.x * c0 - v.y * s0) * sc;
                const float y1 = (v.y * c0 + v.x * s0) * sc;
                const float y2 = (v.z * c1v - v.w * s1) * sc;
                const float y3 = (v.w * c1v + v.z * s1) * sc;
                ushort4 h, l;
                split_bf(y0, h.x, l.x); split_bf(y1, h.y, l.y);
                split_bf(y2, h.z, l.z); split_bf(y3, h.w, l.w);
                const size_t o = (size_t)m * D_MODEL + n0 + c4;
                *(ushort4*)(ohi + o) = h;
                if (z == 0) *(ushort4*)(Qlo + o) = l;   // K needs no lo
            }
        } else {
            const int bb = m0 >> 11;
            #pragma unroll
            for (int i = 0; i < 4; i++) {
                const int cid = i * 256 + t, col = cid >> 3, tg = (cid & 7) * 8;
                ushort u8[8];
                #pragma unroll
                for (int j = 0; j < 8; j++) u8[j] = f2bf(cbuf[(tg + j) * 129 + col]);
                const int ncol = n0 + col, hh = ncol >> 6, d = ncol & 63;
                const size_t dst = ((size_t)(bb * NHEAD + hh) * HEAD_DIM + d) * SEQ +
                                   (m0 & (SEQ - 1)) + p * 64 + tg;
                *(int4*)(VT + dst) = *(int4*)u8;
            }
        }
    }
}

// ---------------------------------------------------------------------------
// Kernel 4: MFMA flash attention, streaming softmax, BARRIER-FREE.
// 32 q-rows per wave (128/block); K/V/mask fragments loaded directly
// global->VGPR in MFMA layout (16B/lane contiguous), software-pipelined one
// tile ahead. maskT float4s serve as the S accumulator's C-init. LDS only
// for the wave-private P (C-layout -> A-layout) round-trip.
// ---------------------------------------------------------------------------
#define KLD 72

__global__ __launch_bounds__(256, 2)
void attn_mfma(const ushort* __restrict__ Qhi, const ushort* __restrict__ Qlo,
               const ushort* __restrict__ Khi,
               const ushort* __restrict__ VT,  const float* __restrict__ maskT,
               float* __restrict__ out)
{
    __shared__ ushort lsP[128 * KLD];   // 18.4 KB

    // 512 blocks: XCD slot = bid&7; 4 (b,h) slabs per slot stay in one L2
    const int bid = blockIdx.x;
    const int bh  = (bid & 7) * 4 + (bid >> 7);
    const int qb  = (bid >> 3) & 15;
    const int b   = bh >> 4, h = bh & 15;
    const int q0  = qb * 128;

    const int t = threadIdx.x, w = t >> 6, lane = t & 63;
    const int lane15 = lane & 15, quad = lane >> 4, quad8 = quad * 8;
    const size_t tok0 = (size_t)b * SEQ;
    const int qw = q0 + w * 32;          // this wave's first q row

    // loop-invariant Q fragments (A-layout), hi/lo, 2 row-groups x 2 k-halves
    bfrag qh[2][2], ql[2][2];
    #pragma unroll
    for (int mi = 0; mi < 2; mi++) {
        const size_t qrow = (tok0 + qw + mi * 16 + lane15) * D_MODEL + h * HEAD_DIM;
        #pragma unroll
        for (int ks = 0; ks < 2; ks++) {
            qh[mi][ks] = *(const bfrag*)(Qhi + qrow + ks * 32 + quad8);
            ql[mi][ks] = *(const bfrag*)(Qlo + qrow + ks * 32 + quad8);
        }
    }

    ffrag of[2][4];
    float l_i[2][4];
    #pragma unroll
    for (int mi = 0; mi < 2; mi++)
        #pragma unroll
        for (int nt = 0; nt < 4; nt++) {
            of[mi][nt] = (ffrag){0.f, 0.f, 0.f, 0.f};
            l_i[mi][nt] = 0.f;   // indexed [mi][rr]
        }

    const ushort* Kb = Khi + tok0 * D_MODEL + h * HEAD_DIM;
    const ushort* Vb = VT + (size_t)(b * NHEAD + h) * HEAD_DIM * SEQ;

    // prefetch tile 0: K frags (B-layout), V frags (B-layout), maskT float4s
    bfrag kf[4][2], vf[4][2];
    float4 mf[2][4];
    #pragma unroll
    for (int nt = 0; nt < 4; nt++)
        #pragma unroll
        for (int ks = 0; ks < 2; ks++) {
            kf[nt][ks] = *(const bfrag*)(Kb + (size_t)(nt * 16 + lane15) * D_MODEL + ks * 32 + quad8);
            vf[nt][ks] = *(const bfrag*)(Vb + (size_t)(nt * 16 + lane15) * SEQ + ks * 32 + quad8);
        }
    #pragma unroll
    for (int mi = 0; mi < 2; mi++)
        #pragma unroll
        for (int nt = 0; nt < 4; nt++)
            mf[mi][nt] = *(const float4*)(maskT + (size_t)(nt * 16 + lane15) * SEQ +
                                          qw + mi * 16 + quad * 4);

    for (int kt = 0; kt < SEQ; kt += 64) {
        const int ktn = (kt + 64 < SEQ) ? kt + 64 : 0;

        // S = (Q/8) K^T + mask   (mask as C-init; hi/lo x2 MFMAs per frag)
        ffrag s[2][4];
        #pragma unroll
        for (int mi = 0; mi < 2; mi++)
            #pragma unroll
            for (int nt = 0; nt < 4; nt++) {
                ffrag a = (ffrag){mf[mi][nt].x, mf[mi][nt].y, mf[mi][nt].z, mf[mi][nt].w};
                #pragma unroll
                for (int ks = 0; ks < 2; ks++) {
                    a = __builtin_amdgcn_mfma_f32_16x16x32_bf16(ql[mi][ks], kf[nt][ks], a, 0, 0, 0);
                    a = __builtin_amdgcn_mfma_f32_16x16x32_bf16(qh[mi][ks], kf[nt][ks], a, 0, 0, 0);
                }
                s[mi][nt] = a;
            }

        // prefetch next tile's K + mask (a full softmax+PV before next use)
        #pragma unroll
        for (int nt = 0; nt < 4; nt++)
            #pragma unroll
            for (int ks = 0; ks < 2; ks++)
                kf[nt][ks] = *(const bfrag*)(Kb + (size_t)(ktn + nt * 16 + lane15) * D_MODEL + ks * 32 + quad8);
        #pragma unroll
        for (int mi = 0; mi < 2; mi++)
            #pragma unroll
            for (int nt = 0; nt < 4; nt++)
                mf[mi][nt] = *(const float4*)(maskT + (size_t)(ktn + nt * 16 + lane15) * SEQ +
                                              qw + mi * 16 + quad * 4);

        // streaming softmax: exp, per-lane l partials, P^T to LDS (bf16)
        #pragma unroll
        for (int mi = 0; mi < 2; mi++)
            #pragma unroll
            for (int nt = 0; nt < 4; nt++)
                #pragma unroll
                for (int rr = 0; rr < 4; rr++) {
                    const float e = __expf(s[mi][nt][rr]);
                    l_i[mi][rr] += e;
                    lsP[(w * 32 + mi * 16 + quad * 4 + rr) * KLD + nt * 16 + lane15] = f2bf(e);
                }

        // O += P V  (P wave-private; V frags already resident)
        #pragma unroll
        for (int mi = 0; mi < 2; mi++)
            #pragma unroll
            for (int ks = 0; ks < 2; ks++) {
                const bfrag pf = *(const bfrag*)&lsP[(w * 32 + mi * 16 + lane15) * KLD + ks * 32 + quad8];
                #pragma unroll
                for (int nt = 0; nt < 4; nt++)
                    of[mi][nt] = __builtin_amdgcn_mfma_f32_16x16x32_bf16(pf, vf[nt][ks], of[mi][nt], 0, 0, 0);
            }

        // prefetch next tile's V (window = next QK + softmax)
        #pragma unroll
        for (int nt = 0; nt < 4; nt++)
            #pragma unroll
            for (int ks = 0; ks < 2; ks++)
                vf[nt][ks] = *(const bfrag*)(Vb + (size_t)(nt * 16 + lane15) * SEQ + ktn + ks * 32 + quad8);
    }

    #pragma unroll
    for (int mi = 0; mi < 2; mi++) {
        float inv[4];
        #pragma unroll
        for (int rr = 0; rr < 4; rr++) {
            float v = l_i[mi][rr];
            #pragma unroll
            for (int off = 1; off < 16; off <<= 1) v += __shfl_xor(v, off);
            inv[rr] = 1.0f / v;
        }
        #pragma unroll
        for (int nt = 0; nt < 4; nt++)
            #pragma unroll
            for (int rr = 0; rr < 4; rr++)
                out[(tok0 + qw + mi * 16 + quad * 4 + rr) * D_MODEL + h * HEAD_DIM +
                    nt * 16 + lane15] = of[mi][nt][rr] * inv[rr];
    }
}

// ---------------------------------------------------------------------------
extern "C" void kernel_launch(void* const* d_in, const int* in_sizes, int n_in,
                              void* d_out, int out_size, void* d_ws, size_t ws_size,
                              hipStream_t stream)
{
    const float* data     = (const float*)d_in[0];
    const float* temporal = (const float*)d_in[1];
    const float* mask     = (const float*)d_in[2];
    const float* Wq = (const float*)d_in[3];
    const float* bq = (const float*)d_in[4];
    const float* Wk = (const float*)d_in[5];
    const float* bk = (const float*)d_in[6];
    const float* Wv = (const float*)d_in[7];
    const float* bv = (const float*)d_in[8];
    float* out = (float*)d_out;

    char* ws = (char*)d_ws;
    const size_t MB = 1024 * 1024;
    ushort* Ahi  = (ushort*)(ws + 0 * MB);    // dead after gemm_qkv
    ushort* Alo  = (ushort*)(ws + 8 * MB);    // dead after gemm_qkv
    float*  maskT = (float*)(ws + 0 * MB);    // overwrites Ahi/Alo (16.8 MB)
    ushort* WThi = (ushort*)(ws + 17 * MB);   // 6 MB (3x1024x1024 bf16)
    ushort* Qhi  = (ushort*)(ws + 28 * MB);
    ushort* Qlo  = (ushort*)(ws + 36 * MB);
    ushort* Khi  = (ushort*)(ws + 44 * MB);
    ushort* VT   = (ushort*)(ws + 60 * MB);

    split_data<<<dim3(NTOK * D_MODEL / 1024), 256, 0, stream>>>(data, Ahi, Alo);
    split_tr_w<<<dim3(16, 16, 3), 256, 0, stream>>>(Wq, Wk, Wv, WThi);
    gemm_qkv<<<dim3(NTOK / 128, D_MODEL / 128, 3), 256, 0, stream>>>(
        Ahi, Alo, WThi, bq, bk, bv, temporal,
        Qhi, Qlo, Khi, VT);
    tr_mask<<<dim3(SEQ / 64, SEQ / 64), 256, 0, stream>>>(mask, maskT);
    attn_mfma<<<dim3(BATCH * NHEAD * SEQ / 128), 256, 0, stream>>>(
        Qhi, Qlo, Khi, VT, maskT, out);
}